// Round 1
// baseline (161.279 us; speedup 1.0000x reference)
//
#include <hip/hip_runtime.h>
#include <math.h>

#define NT 50      // targets per image
#define NG 64      // grid
#define NCLS 91
#define NCH 96     // 5 + 91

// anchors / STRIDE(8)
__device__ __constant__ float c_aw[9] = {1.25f, 2.0f, 4.125f, 3.75f, 7.75f, 7.375f, 14.5f, 19.5f, 46.625f};
__device__ __constant__ float c_ah[9] = {1.625f, 3.75f, 2.875f, 7.625f, 5.625f, 14.875f, 11.25f, 24.75f, 40.75f};

__device__ __forceinline__ float softplusf(float x) {
    // stable: log1p(exp(-|x|)) + max(x,0)
    return log1pf(expf(-fabsf(x))) + fmaxf(x, 0.0f);
}

__global__ __launch_bounds__(256) void yolo_scale_loss_kernel(
        const float* __restrict__ out, const float* __restrict__ lab,
        float* __restrict__ loss_out) {
    __shared__ float s_xc[NT], s_yc[NT], s_hw[NT], s_hh[NT], s_area[NT], s_valid[NT];
    __shared__ int   s_cell[NT], s_cls[NT];
    __shared__ float s_t0[NT], s_t1[NT], s_t2[NT], s_t3[NT], s_s2[NT];
    __shared__ float s_red[4];

    const int b   = blockIdx.y;
    const int tid = threadIdx.x;

    // ---- per-target precompute (threads 0..49) ----
    if (tid < NT) {
        const float* L = lab + (size_t)(b * NT + tid) * 5;
        float cls = L[0], x = L[1], y = L[2], w = L[3], h = L[4];
        float tx = x * NG, ty = y * NG, tw = w * NG, th = h * NG;
        bool valid = (cls + x + y + w + h) > 0.0f;
        float twth = tw * th;

        // argmax anchor IoU over 9 anchors (first-max wins, like jnp.argmax)
        float best = -1.0f; int bn_all = 0;
        #pragma unroll
        for (int k = 0; k < 9; ++k) {
            float mw = fminf(tw, c_aw[k]);
            float mh = fminf(th, c_ah[k]);
            float inter = (mw > 0.0f && mh > 0.0f) ? mw * mh : 0.0f;
            float iou = inter / (twth + c_aw[k] * c_ah[k] - inter);
            if (iou > best) { best = iou; bn_all = k; }
        }
        bool mask = valid && (bn_all < 3);   // ANCH_MASK = [0,1,2]
        int bn = bn_all % 3;
        int ii = (int)tx;   // trunc; tx in [3.2, 60.8] for valid targets
        int jj = (int)ty;

        s_xc[tid] = tx; s_yc[tid] = ty;
        s_hw[tid] = tw * 0.5f; s_hh[tid] = th * 0.5f;
        s_area[tid] = twth;
        s_valid[tid] = valid ? 1.0f : 0.0f;
        s_cell[tid] = mask ? (bn_all * 4096 + jj * 64 + ii) : -1;
        s_t0[tid] = tx - floorf(tx);
        s_t1[tid] = ty - floorf(ty);
        s_t2[tid] = logf(tw / c_aw[bn] + 1e-16f);
        s_t3[tid] = logf(th / c_ah[bn] + 1e-16f);
        s_s2[tid] = 2.0f - twth * (1.0f / (NG * NG));  // tgt_scale^2
        s_cls[tid] = (int)cls;
    }
    __syncthreads();

    // ---- per-cell work ----
    const int idx = blockIdx.x * 256 + tid;            // 0..12287 within image
    const int a = idx >> 12;
    const int j = (idx >> 6) & 63;
    const int i = idx & 63;
    const size_t base = ((size_t)b * 12288 + idx) * NCH;

    const float4 p03 = *(const float4*)(out + base);   // 384B stride -> 16B aligned
    const float  p4  = out[base + 4];

    // predicted box
    float pxc = 1.0f / (1.0f + expf(-p03.x)) + (float)i;
    float pyc = 1.0f / (1.0f + expf(-p03.y)) + (float)j;
    float pw  = expf(p03.z) * c_aw[a];
    float ph  = expf(p03.w) * c_ah[a];
    float phw = pw * 0.5f, phh = ph * 0.5f;
    float parea = pw * ph;

    // ignore-mask: max IoU vs all valid targets; winner: first matching target
    float maxiou = 0.0f;
    int winner = -1;
    #pragma unroll 5
    for (int t = 0; t < NT; ++t) {
        float tlx = fmaxf(pxc - phw, s_xc[t] - s_hw[t]);
        float tly = fmaxf(pyc - phh, s_yc[t] - s_hh[t]);
        float brx = fminf(pxc + phw, s_xc[t] + s_hw[t]);
        float bry = fminf(pyc + phh, s_yc[t] + s_hh[t]);
        float iw = brx - tlx, ih = bry - tly;
        float ai = (iw > 0.0f && ih > 0.0f) ? iw * ih : 0.0f;
        float iou = ai / (parea + s_area[t] - ai) * s_valid[t];
        maxiou = fmaxf(maxiou, iou);
        if (winner < 0 && s_cell[t] == idx) winner = t;
    }

    float loss;
    if (winner >= 0) {
        // matched cell: obj_mask=1, tmask=1, targets from winning label
        loss  = softplusf(p4) - p4;                               // obj target = 1
        loss += softplusf(p03.x) - p03.x * s_t0[winner];
        loss += softplusf(p03.y) - p03.y * s_t1[winner];
        float d2 = p03.z - s_t2[winner];
        float d3 = p03.w - s_t3[winner];
        loss += 0.5f * s_s2[winner] * (d2 * d2 + d3 * d3);
        int cc = s_cls[winner];
        for (int c = 0; c < NCLS; ++c) {
            float pc = out[base + 5 + c];
            loss += softplusf(pc) - ((c == cc) ? pc : 0.0f);
        }
    } else {
        // unmatched: obj loss only where not ignored (target 0)
        loss = (maxiou > 0.5f) ? 0.0f : softplusf(p4);
    }

    // ---- block reduction ----
    #pragma unroll
    for (int off = 32; off > 0; off >>= 1)
        loss += __shfl_down(loss, off, 64);
    if ((tid & 63) == 0) s_red[tid >> 6] = loss;
    __syncthreads();
    if (tid == 0)
        atomicAdd(loss_out, s_red[0] + s_red[1] + s_red[2] + s_red[3]);
}

extern "C" void kernel_launch(void* const* d_in, const int* in_sizes, int n_in,
                              void* d_out, int out_size, void* d_ws, size_t ws_size,
                              hipStream_t stream) {
    const float* out = (const float*)d_in[0];
    const float* lab = (const float*)d_in[1];
    float* res = (float*)d_out;

    const int B = in_sizes[1] / (NT * 5);   // 16

    hipMemsetAsync(d_out, 0, sizeof(float), stream);
    dim3 grid(12288 / 256, B);              // 48 x 16 blocks, 256 threads
    yolo_scale_loss_kernel<<<grid, 256, 0, stream>>>(out, lab, res);
}

// Round 2
// 112.130 us; speedup vs baseline: 1.4383x; 1.4383x over previous
//
#include <hip/hip_runtime.h>
#include <math.h>

#define NT 50      // targets per image
#define NG 64      // grid
#define NCLS 91
#define NCH 96     // 5 + 91
#define CELL_BLOCKS 48   // 12288 cells / 256 threads
#define TGT_BLOCKS  13   // ceil(50 waves / 4 waves-per-block)

// anchors / STRIDE(8)
__device__ __constant__ float c_aw[9] = {1.25f, 2.0f, 4.125f, 3.75f, 7.75f, 7.375f, 14.5f, 19.5f, 46.625f};
__device__ __constant__ float c_ah[9] = {1.625f, 3.75f, 2.875f, 7.625f, 5.625f, 14.875f, 11.25f, 24.75f, 40.75f};

__device__ __forceinline__ float softplusf_fast(float x) {
    // log1p(exp(-|x|)) + max(x,0); fast intrinsics — rel err ~1e-6, fine vs 2785 abs tol
    return __logf(1.0f + __expf(-fabsf(x))) + fmaxf(x, 0.0f);
}

// per-target: anchor-IoU argmax over 9 anchors → mask / cell / best anchor
__device__ __forceinline__ void target_match(float tw, float th, bool valid,
                                             float tx, float ty,
                                             bool& mask, int& cell, int& bn) {
    float area = tw * th;
    float best = -1.0f; int bna = 0;
    #pragma unroll
    for (int k = 0; k < 9; ++k) {
        float mw = fminf(tw, c_aw[k]);
        float mh = fminf(th, c_ah[k]);
        float inter = (mw > 0.0f && mh > 0.0f) ? mw * mh : 0.0f;
        float iou = inter / (area + c_aw[k] * c_ah[k] - inter);
        if (iou > best) { best = iou; bna = k; }
    }
    mask = valid && (bna < 3);    // ANCH_MASK = [0,1,2]
    bn = bna;                     // == bna % 3 when mask
    cell = mask ? (bna * 4096 + ((int)ty) * 64 + (int)tx) : -1;
}

__global__ __launch_bounds__(256) void yolo_scale_loss_kernel(
        const float* __restrict__ outp, const float* __restrict__ lab,
        float* __restrict__ loss_out) {
    const int b    = blockIdx.y;
    const int tid  = threadIdx.x;
    const int lane = tid & 63;

    if (blockIdx.x < CELL_BLOCKS) {
        // ================= cell role: obj loss for 256 cells =================
        __shared__ float4 s_box[NT];   // lx, ly, rx, ry
        __shared__ int2   s_meta[NT];  // x = area bits, y = matched-cell id (-1 if none)
        __shared__ float  s_red[4];

        if (tid < NT) {
            const float* L = lab + (size_t)(b * NT + tid) * 5;
            float cls = L[0], x = L[1], y = L[2], w = L[3], h = L[4];
            float tx = x * NG, ty = y * NG, tw = w * NG, th = h * NG;
            bool valid = (cls + x + y + w + h) > 0.0f;
            if (!valid) { tx = ty = tw = th = 0.0f; }
            bool mask; int cell, bn;
            target_match(tw, th, valid, tx, ty, mask, cell, bn);
            float hw = tw * 0.5f, hh = th * 0.5f;
            s_box[tid]  = make_float4(tx - hw, ty - hh, tx + hw, ty + hh);
            s_meta[tid] = make_int2(__float_as_int(tw * th), cell);
        }
        __syncthreads();

        const int idx = blockIdx.x * 256 + tid;         // cell within image
        const int a = idx >> 12;
        const int j = (idx >> 6) & 63;
        const int i = idx & 63;
        const size_t base = ((size_t)b * 12288 + idx) * NCH;

        const float4 p03 = *(const float4*)(outp + base);  // 384B row stride → aligned
        const float  p4  = outp[base + 4];

        float pxc = 1.0f / (1.0f + __expf(-p03.x)) + (float)i;
        float pyc = 1.0f / (1.0f + __expf(-p03.y)) + (float)j;
        float pw  = __expf(p03.z) * c_aw[a];
        float ph  = __expf(p03.w) * c_ah[a];
        float parea = pw * ph;
        float pl = pxc - pw * 0.5f, pt = pyc - ph * 0.5f;
        float pr = pxc + pw * 0.5f, pb = pyc + ph * 0.5f;

        bool ign = false, matched = false;
        #pragma unroll 5
        for (int t = 0; t < NT; ++t) {
            float4 tb = s_box[t];
            int2   m  = s_meta[t];
            float tlx = fmaxf(pl, tb.x), tly = fmaxf(pt, tb.y);
            float brx = fminf(pr, tb.z), bry = fminf(pb, tb.w);
            float iw = brx - tlx, ih = bry - tly;
            float ai = (iw > 0.0f && ih > 0.0f) ? iw * ih : 0.0f;
            float den = parea + __int_as_float(m.x) - ai;
            ign     = ign     || (ai + ai > den);       // iou > 0.5, division-free
            matched = matched || (m.y == idx);
        }
        float loss = matched ? (softplusf_fast(p4) - p4)
                             : (ign ? 0.0f : softplusf_fast(p4));

        #pragma unroll
        for (int off = 32; off > 0; off >>= 1)
            loss += __shfl_down(loss, off, 64);
        if (lane == 0) s_red[tid >> 6] = loss;
        __syncthreads();
        if (tid == 0)
            atomicAdd(loss_out, s_red[0] + s_red[1] + s_red[2] + s_red[3]);
    } else {
        // ============ target role: one wave per (b, t) — xy/wh/cls ============
        const int t = (blockIdx.x - CELL_BLOCKS) * 4 + (tid >> 6);
        if (t >= NT) return;                              // wave-uniform exit

        // lane l computes target-l info for this image (for dedup ballot)
        bool mask_l = false; int cell_l = -1, bn_l = 0, cls_l = 0;
        float txl = 0, tyl = 0, twl = 0, thl = 0;
        if (lane < NT) {
            const float* L = lab + (size_t)(b * NT + lane) * 5;
            float cls = L[0], x = L[1], y = L[2], w = L[3], h = L[4];
            txl = x * NG; tyl = y * NG; twl = w * NG; thl = h * NG;
            bool valid = (cls + x + y + w + h) > 0.0f;
            target_match(twl, thl, valid, txl, tyl, mask_l, cell_l, bn_l);
            cls_l = (int)cls;
        }
        const int cell_t = __shfl(cell_l, t);
        unsigned long long same = __ballot(mask_l && (cell_l == cell_t));
        // first-target-wins dedup (matches round-1 semantics, absmax was 0.0)
        bool winner = ((same >> t) & 1ull) && ((same & ((1ull << t) - 1ull)) == 0ull);
        if (!winner) return;                              // wave-uniform

        const float tx = __shfl(txl, t), ty = __shfl(tyl, t);
        const float tw = __shfl(twl, t), th = __shfl(thl, t);
        const int   bn = __shfl(bn_l, t), cc = __shfl(cls_l, t);
        const size_t base = ((size_t)b * 12288 + cell_t) * NCH;

        float lsum = 0.0f;
        // 91 class channels, coalesced across lanes (2 rounds: 64 + 27)
        for (int c = lane; c < NCLS; c += 64) {
            float pc = outp[base + 5 + c];
            lsum += softplusf_fast(pc) - ((c == cc) ? pc : 0.0f);
        }
        if (lane == 0) {
            float4 p03 = *(const float4*)(outp + base);
            float t0 = tx - floorf(tx), t1 = ty - floorf(ty);
            float t2 = logf(tw / c_aw[bn] + 1e-16f);
            float t3 = logf(th / c_ah[bn] + 1e-16f);
            float s2 = 2.0f - tw * th * (1.0f / (NG * NG));   // tgt_scale^2
            lsum += softplusf_fast(p03.x) - p03.x * t0;
            lsum += softplusf_fast(p03.y) - p03.y * t1;
            float d2 = p03.z - t2, d3 = p03.w - t3;
            lsum += 0.5f * s2 * (d2 * d2 + d3 * d3);
        }
        #pragma unroll
        for (int off = 32; off > 0; off >>= 1)
            lsum += __shfl_down(lsum, off, 64);
        if (lane == 0) atomicAdd(loss_out, lsum);
    }
}

extern "C" void kernel_launch(void* const* d_in, const int* in_sizes, int n_in,
                              void* d_out, int out_size, void* d_ws, size_t ws_size,
                              hipStream_t stream) {
    const float* outp = (const float*)d_in[0];
    const float* lab  = (const float*)d_in[1];
    float* res = (float*)d_out;

    const int B = in_sizes[1] / (NT * 5);   // 16

    hipMemsetAsync(d_out, 0, sizeof(float), stream);
    dim3 grid(CELL_BLOCKS + TGT_BLOCKS, B);   // (61, 16)
    yolo_scale_loss_kernel<<<grid, 256, 0, stream>>>(outp, lab, res);
}

// Round 3
// 110.734 us; speedup vs baseline: 1.4565x; 1.0126x over previous
//
#include <hip/hip_runtime.h>
#include <math.h>

#define NT 50      // targets per image
#define NG 64      // grid
#define NCLS 91
#define NCH 96     // 5 + 91
#define CELL_BLOCKS 48   // 12288 cells / 256 threads
#define TGT_BLOCKS  13   // ceil(50 waves / 4 waves-per-block)
#define BX (CELL_BLOCKS + TGT_BLOCKS)   // 61
#define NPART (BX * 16)                  // 976 partials

// anchors / STRIDE(8)
__device__ __constant__ float c_aw[9] = {1.25f, 2.0f, 4.125f, 3.75f, 7.75f, 7.375f, 14.5f, 19.5f, 46.625f};
__device__ __constant__ float c_ah[9] = {1.625f, 3.75f, 2.875f, 7.625f, 5.625f, 14.875f, 11.25f, 24.75f, 40.75f};

__device__ __forceinline__ float softplusf_fast(float x) {
    return __logf(1.0f + __expf(-fabsf(x))) + fmaxf(x, 0.0f);
}

__device__ __forceinline__ void target_match(float tw, float th, bool valid,
                                             float tx, float ty,
                                             bool& mask, int& cell, int& bn) {
    float area = tw * th;
    float best = -1.0f; int bna = 0;
    #pragma unroll
    for (int k = 0; k < 9; ++k) {
        float mw = fminf(tw, c_aw[k]);
        float mh = fminf(th, c_ah[k]);
        float inter = (mw > 0.0f && mh > 0.0f) ? mw * mh : 0.0f;
        float iou = inter / (area + c_aw[k] * c_ah[k] - inter);
        if (iou > best) { best = iou; bna = k; }
    }
    mask = valid && (bna < 3);    // ANCH_MASK = [0,1,2]
    bn = bna;                     // == bna % 3 when mask
    cell = mask ? (bna * 4096 + ((int)ty) * 64 + (int)tx) : -1;
}

__global__ __launch_bounds__(256) void yolo_scale_loss_kernel(
        const float* __restrict__ outp, const float* __restrict__ lab,
        float* __restrict__ partials) {
    const int b    = blockIdx.y;
    const int tid  = threadIdx.x;
    const int lane = tid & 63;
    __shared__ float s_red[4];

    float block_sum_contrib;   // per-thread loss, reduced at the end

    if (blockIdx.x < CELL_BLOCKS) {
        // ================= cell role: obj loss for 256 cells =================
        __shared__ float4 s_box[NT];   // lx, ly, rx, ry
        __shared__ int2   s_meta[NT];  // x = area bits, y = matched-cell id (-1)

        const int idx = blockIdx.x * 256 + tid;         // cell within image
        const size_t base = ((size_t)b * 12288 + idx) * NCH;

        // issue global loads BEFORE the barrier so HBM latency overlaps
        const float4 p03 = *(const float4*)(outp + base);  // 384B stride → aligned
        const float  p4  = outp[base + 4];

        if (tid < NT) {
            const float* L = lab + (size_t)(b * NT + tid) * 5;
            float cls = L[0], x = L[1], y = L[2], w = L[3], h = L[4];
            float tx = x * NG, ty = y * NG, tw = w * NG, th = h * NG;
            bool valid = (cls + x + y + w + h) > 0.0f;
            if (!valid) { tx = ty = tw = th = 0.0f; }
            bool mask; int cell, bn;
            target_match(tw, th, valid, tx, ty, mask, cell, bn);
            float hw = tw * 0.5f, hh = th * 0.5f;
            s_box[tid]  = make_float4(tx - hw, ty - hh, tx + hw, ty + hh);
            s_meta[tid] = make_int2(__float_as_int(tw * th), cell);
        }
        __syncthreads();

        const int a = idx >> 12;
        const int j = (idx >> 6) & 63;
        const int i = idx & 63;

        float pxc = 1.0f / (1.0f + __expf(-p03.x)) + (float)i;
        float pyc = 1.0f / (1.0f + __expf(-p03.y)) + (float)j;
        float pw  = __expf(p03.z) * c_aw[a];
        float ph  = __expf(p03.w) * c_ah[a];
        float parea = pw * ph;
        float pl = pxc - pw * 0.5f, pt = pyc - ph * 0.5f;
        float pr = pxc + pw * 0.5f, pb = pyc + ph * 0.5f;

        bool ign = false, matched = false;
        #pragma unroll 5
        for (int t = 0; t < NT; ++t) {
            float4 tb = s_box[t];
            int2   m  = s_meta[t];
            float tlx = fmaxf(pl, tb.x), tly = fmaxf(pt, tb.y);
            float brx = fminf(pr, tb.z), bry = fminf(pb, tb.w);
            float iw = brx - tlx, ih = bry - tly;
            float ai = (iw > 0.0f && ih > 0.0f) ? iw * ih : 0.0f;
            float den = parea + __int_as_float(m.x) - ai;
            ign     = ign     || (ai + ai > den);       // iou > 0.5, div-free
            matched = matched || (m.y == idx);
        }
        block_sum_contrib = matched ? (softplusf_fast(p4) - p4)
                                    : (ign ? 0.0f : softplusf_fast(p4));
    } else {
        // ============ target role: one wave per (b, t) — xy/wh/cls ============
        const int t = (blockIdx.x - CELL_BLOCKS) * 4 + (tid >> 6);
        float lsum = 0.0f;
        if (t < NT) {                                     // wave-uniform
            bool mask_l = false; int cell_l = -1, bn_l = 0, cls_l = 0;
            float txl = 0, tyl = 0, twl = 0, thl = 0;
            if (lane < NT) {
                const float* L = lab + (size_t)(b * NT + lane) * 5;
                float cls = L[0], x = L[1], y = L[2], w = L[3], h = L[4];
                txl = x * NG; tyl = y * NG; twl = w * NG; thl = h * NG;
                bool valid = (cls + x + y + w + h) > 0.0f;
                target_match(twl, thl, valid, txl, tyl, mask_l, cell_l, bn_l);
                cls_l = (int)cls;
            }
            const int cell_t = __shfl(cell_l, t);
            unsigned long long same = __ballot(mask_l && (cell_l == cell_t));
            // first-target-wins dedup (absmax 0.0 in rounds 1-2)
            bool winner = ((same >> t) & 1ull) &&
                          ((same & ((1ull << t) - 1ull)) == 0ull);
            if (winner) {                                 // wave-uniform
                const float tx = __shfl(txl, t), ty = __shfl(tyl, t);
                const float tw = __shfl(twl, t), th = __shfl(thl, t);
                const int   bn = __shfl(bn_l, t), cc = __shfl(cls_l, t);
                const size_t base = ((size_t)b * 12288 + cell_t) * NCH;

                // 91 class channels, coalesced across lanes (64 + 27)
                for (int c = lane; c < NCLS; c += 64) {
                    float pc = outp[base + 5 + c];
                    lsum += softplusf_fast(pc) - ((c == cc) ? pc : 0.0f);
                }
                if (lane == 0) {
                    float4 p03 = *(const float4*)(outp + base);
                    float t0 = tx - floorf(tx), t1 = ty - floorf(ty);
                    float t2 = logf(tw / c_aw[bn] + 1e-16f);
                    float t3 = logf(th / c_ah[bn] + 1e-16f);
                    float s2 = 2.0f - tw * th * (1.0f / (NG * NG));
                    lsum += softplusf_fast(p03.x) - p03.x * t0;
                    lsum += softplusf_fast(p03.y) - p03.y * t1;
                    float d2 = p03.z - t2, d3 = p03.w - t3;
                    lsum += 0.5f * s2 * (d2 * d2 + d3 * d3);
                }
            }
        }
        block_sum_contrib = lsum;
    }

    // ---- block reduction → one partial per block (no global atomics) ----
    float v = block_sum_contrib;
    #pragma unroll
    for (int off = 32; off > 0; off >>= 1)
        v += __shfl_down(v, off, 64);
    if (lane == 0) s_red[tid >> 6] = v;
    __syncthreads();
    if (tid == 0)
        partials[blockIdx.y * BX + blockIdx.x] = s_red[0] + s_red[1] + s_red[2] + s_red[3];
}

__global__ __launch_bounds__(256) void final_reduce_kernel(
        const float* __restrict__ partials, float* __restrict__ out) {
    __shared__ float s_red[4];
    const int tid = threadIdx.x, lane = tid & 63;
    float v = 0.0f;
    for (int i = tid; i < NPART; i += 256) v += partials[i];
    #pragma unroll
    for (int off = 32; off > 0; off >>= 1)
        v += __shfl_down(v, off, 64);
    if (lane == 0) s_red[tid >> 6] = v;
    __syncthreads();
    if (tid == 0) out[0] = s_red[0] + s_red[1] + s_red[2] + s_red[3];
}

extern "C" void kernel_launch(void* const* d_in, const int* in_sizes, int n_in,
                              void* d_out, int out_size, void* d_ws, size_t ws_size,
                              hipStream_t stream) {
    const float* outp = (const float*)d_in[0];
    const float* lab  = (const float*)d_in[1];
    float* partials   = (float*)d_ws;
    float* res        = (float*)d_out;

    const int B = in_sizes[1] / (NT * 5);   // 16

    dim3 grid(BX, B);                        // (61, 16)
    yolo_scale_loss_kernel<<<grid, 256, 0, stream>>>(outp, lab, partials);
    final_reduce_kernel<<<1, 256, 0, stream>>>(partials, res);
}

// Round 4
// 109.423 us; speedup vs baseline: 1.4739x; 1.0120x over previous
//
#include <hip/hip_runtime.h>
#include <math.h>

#define NT 50      // targets per image
#define NG 64      // grid
#define NCLS 91
#define NCH 96     // 5 + 91
#define CPB 128    // cells per block (2 threads per cell, 256-thread blocks)
#define CELL_BLOCKS 96   // 12288 / 128
#define TGT_BLOCKS  13   // ceil(50 waves / 4 waves-per-block)
#define BX (CELL_BLOCKS + TGT_BLOCKS)   // 109
#define NPART (BX * 16)                 // 1744 partials

// anchors / STRIDE(8)
__device__ __constant__ float c_aw[9] = {1.25f, 2.0f, 4.125f, 3.75f, 7.75f, 7.375f, 14.5f, 19.5f, 46.625f};
__device__ __constant__ float c_ah[9] = {1.625f, 3.75f, 2.875f, 7.625f, 5.625f, 14.875f, 11.25f, 24.75f, 40.75f};

__device__ __forceinline__ float softplusf_fast(float x) {
    return __logf(1.0f + __expf(-fabsf(x))) + fmaxf(x, 0.0f);
}

__device__ __forceinline__ void target_match(float tw, float th, bool valid,
                                             float tx, float ty,
                                             bool& mask, int& cell, int& bn) {
    float area = tw * th;
    float best = -1.0f; int bna = 0;
    #pragma unroll
    for (int k = 0; k < 9; ++k) {
        float mw = fminf(tw, c_aw[k]);
        float mh = fminf(th, c_ah[k]);
        float inter = (mw > 0.0f && mh > 0.0f) ? mw * mh : 0.0f;
        float iou = inter / (area + c_aw[k] * c_ah[k] - inter);
        if (iou > best) { best = iou; bna = k; }
    }
    mask = valid && (bna < 3);    // ANCH_MASK = [0,1,2]
    bn = bna;                     // == bna % 3 when mask
    cell = mask ? (bna * 4096 + ((int)ty) * 64 + (int)tx) : -1;
}

__global__ __launch_bounds__(256) void yolo_scale_loss_kernel(
        const float* __restrict__ outp, const float* __restrict__ lab,
        float* __restrict__ partials) {
    const int b    = blockIdx.y;
    const int tid  = threadIdx.x;
    const int lane = tid & 63;
    __shared__ float s_red[4];

    float contrib = 0.0f;

    if (blockIdx.x < CELL_BLOCKS) {
        // ====== cell role: obj loss; 2 threads per cell (25 targets each) ======
        __shared__ float4 s_box[NT];            // lx, ly, rx, ry
        __shared__ float  s_area[NT];
        __shared__ unsigned char s_matched[CPB];

        const int cell_local = tid >> 1;        // 0..127
        const int half = tid & 1;               // which 25-target slice
        const int blk_start = blockIdx.x * CPB;
        const int idx = blk_start + cell_local; // cell within image
        const size_t base = ((size_t)b * 12288 + idx) * NCH;

        // issue global loads BEFORE the barrier so HBM latency overlaps precompute
        const float4 p03 = *(const float4*)(outp + base);
        const float  p4  = outp[base + 4];

        if (tid < CPB) s_matched[tid] = 0;
        if (tid < NT) {
            const float* L = lab + (size_t)(b * NT + tid) * 5;
            float cls = L[0], x = L[1], y = L[2], w = L[3], h = L[4];
            float tx = x * NG, ty = y * NG, tw = w * NG, th = h * NG;
            bool valid = (cls + x + y + w + h) > 0.0f;
            if (!valid) { tx = ty = tw = th = 0.0f; }   // degenerate box: never ignites IoU
            bool mask; int cell, bn;
            target_match(tw, th, valid, tx, ty, mask, cell, bn);
            float hw = tw * 0.5f, hh = th * 0.5f;
            s_box[tid]  = make_float4(tx - hw, ty - hh, tx + hw, ty + hh);
            s_area[tid] = tw * th;
            if (cell >= blk_start && cell < blk_start + CPB)
                s_matched[cell - blk_start] = 1;        // benign races, all write 1
        }
        __syncthreads();

        const int a = idx >> 12;
        const int j = (idx >> 6) & 63;
        const int i = idx & 63;

        float pxc = 1.0f / (1.0f + __expf(-p03.x)) + (float)i;
        float pyc = 1.0f / (1.0f + __expf(-p03.y)) + (float)j;
        float pw  = __expf(p03.z) * c_aw[a];
        float ph  = __expf(p03.w) * c_ah[a];
        float parea = pw * ph;
        float pl = pxc - pw * 0.5f, pt = pyc - ph * 0.5f;
        float pr = pxc + pw * 0.5f, pb = pyc + ph * 0.5f;

        bool ign = false;
        const int t0 = half * 25;
        #pragma unroll 5
        for (int k = 0; k < 25; ++k) {
            float4 tb = s_box[t0 + k];
            float  ar = s_area[t0 + k];
            float tlx = fmaxf(pl, tb.x), tly = fmaxf(pt, tb.y);
            float brx = fminf(pr, tb.z), bry = fminf(pb, tb.w);
            float iw = brx - tlx, ih = bry - tly;
            float ai = iw * ih;
            // iou>0.5 ⇔ 2ai > parea+ar−ai ⇔ 3ai > parea+ar (den>0 always)
            ign = ign || ((fminf(iw, ih) > 0.0f) && (3.0f * ai > parea + ar));
        }
        int ign_i = ign ? 1 : 0;
        ign_i |= __shfl_xor(ign_i, 1, 64);      // combine the two 25-target halves

        if (half == 0) {
            bool matched = (s_matched[cell_local] != 0);
            contrib = matched ? (softplusf_fast(p4) - p4)
                              : (ign_i ? 0.0f : softplusf_fast(p4));
        }
    } else {
        // ============ target role: one wave per (b, t) — xy/wh/cls ============
        const int t = (blockIdx.x - CELL_BLOCKS) * 4 + (tid >> 6);
        if (t < NT) {                                     // wave-uniform
            bool mask_l = false; int cell_l = -1, bn_l = 0, cls_l = 0;
            float txl = 0, tyl = 0, twl = 0, thl = 0;
            if (lane < NT) {
                const float* L = lab + (size_t)(b * NT + lane) * 5;
                float cls = L[0], x = L[1], y = L[2], w = L[3], h = L[4];
                txl = x * NG; tyl = y * NG; twl = w * NG; thl = h * NG;
                bool valid = (cls + x + y + w + h) > 0.0f;
                target_match(twl, thl, valid, txl, tyl, mask_l, cell_l, bn_l);
                cls_l = (int)cls;
            }
            const int cell_t = __shfl(cell_l, t);
            unsigned long long same = __ballot(mask_l && (cell_l == cell_t));
            // first-target-wins dedup (absmax 0.0 rounds 1-3)
            bool winner = ((same >> t) & 1ull) &&
                          ((same & ((1ull << t) - 1ull)) == 0ull);
            if (winner) {                                 // wave-uniform
                const float tx = __shfl(txl, t), ty = __shfl(tyl, t);
                const float tw = __shfl(twl, t), th = __shfl(thl, t);
                const int   bn = __shfl(bn_l, t), cc = __shfl(cls_l, t);
                const size_t base = ((size_t)b * 12288 + cell_t) * NCH;

                float lsum = 0.0f;
                for (int c = lane; c < NCLS; c += 64) {   // coalesced 64 + 27
                    float pc = outp[base + 5 + c];
                    lsum += softplusf_fast(pc) - ((c == cc) ? pc : 0.0f);
                }
                if (lane == 0) {
                    float4 p03 = *(const float4*)(outp + base);
                    float tt0 = tx - floorf(tx), tt1 = ty - floorf(ty);
                    float tt2 = logf(tw / c_aw[bn] + 1e-16f);
                    float tt3 = logf(th / c_ah[bn] + 1e-16f);
                    float s2 = 2.0f - tw * th * (1.0f / (NG * NG));
                    lsum += softplusf_fast(p03.x) - p03.x * tt0;
                    lsum += softplusf_fast(p03.y) - p03.y * tt1;
                    float d2 = p03.z - tt2, d3 = p03.w - tt3;
                    lsum += 0.5f * s2 * (d2 * d2 + d3 * d3);
                }
                contrib = lsum;
            }
        }
    }

    // ---- block reduction → one partial per block (no global atomics) ----
    float v = contrib;
    #pragma unroll
    for (int off = 32; off > 0; off >>= 1)
        v += __shfl_down(v, off, 64);
    if (lane == 0) s_red[tid >> 6] = v;
    __syncthreads();
    if (tid == 0)
        partials[blockIdx.y * BX + blockIdx.x] = s_red[0] + s_red[1] + s_red[2] + s_red[3];
}

__global__ __launch_bounds__(256) void final_reduce_kernel(
        const float* __restrict__ partials, float* __restrict__ out) {
    __shared__ float s_red[4];
    const int tid = threadIdx.x, lane = tid & 63;
    float v = 0.0f;
    for (int i = tid; i < NPART; i += 256) v += partials[i];
    #pragma unroll
    for (int off = 32; off > 0; off >>= 1)
        v += __shfl_down(v, off, 64);
    if (lane == 0) s_red[tid >> 6] = v;
    __syncthreads();
    if (tid == 0) out[0] = s_red[0] + s_red[1] + s_red[2] + s_red[3];
}

extern "C" void kernel_launch(void* const* d_in, const int* in_sizes, int n_in,
                              void* d_out, int out_size, void* d_ws, size_t ws_size,
                              hipStream_t stream) {
    const float* outp = (const float*)d_in[0];
    const float* lab  = (const float*)d_in[1];
    float* partials   = (float*)d_ws;
    float* res        = (float*)d_out;

    const int B = in_sizes[1] / (NT * 5);   // 16

    dim3 grid(BX, B);                        // (109, 16)
    yolo_scale_loss_kernel<<<grid, 256, 0, stream>>>(outp, lab, partials);
    final_reduce_kernel<<<1, 256, 0, stream>>>(partials, res);
}